// Round 4
// baseline (485.285 us; speedup 1.0000x reference)
//
#include <hip/hip_runtime.h>
#include <hip/hip_fp16.h>
#include <math.h>

#define N_NODES   50000
#define N_EDGES   1600000
#define E_TOT     (N_EDGES + N_NODES)
#define N_FEAT    128
#define HIDDEN    64
#define N_GRAPHS  128
#define NEG_SLOPE 0.2f
#define NB_SCAN   ((N_NODES + 1023) / 1024)
#define OCT_N     (N_NODES / 8)          // 6250, exact
#define FB_GRP    96                     // edge-slices per octant
#define FB_CE     ((E_TOT + FB_GRP - 1) / FB_GRP)

// ---- monotone float<->uint encoding for atomicMax on floats ----
__device__ __forceinline__ unsigned fenc(float f) {
    unsigned u = __float_as_uint(f);
    return (u & 0x80000000u) ? ~u : (u | 0x80000000u);
}
__device__ __forceinline__ float fdec(unsigned k) {
    unsigned u = (k & 0x80000000u) ? (k & 0x7FFFFFFFu) : ~k;
    return __uint_as_float(u);
}
__device__ __forceinline__ float lrelu(float e) {
    return (e >= 0.f) ? e : NEG_SLOPE * e;
}

// ---- fold: W2C1 = w2 @ c1w ; B2C1 = b2 @ c1w (one block) ----
__global__ __launch_bounds__(256) void fold_w(
    const float* __restrict__ w2, const float* __restrict__ b2,
    const float* __restrict__ c1w,
    float* __restrict__ w2c1, float* __restrict__ b2c1)
{
    __shared__ float c1s[64 * 64];
    int tid = threadIdx.x;
    for (int i = tid; i < 4096; i += 256) c1s[i] = c1w[i];
    __syncthreads();
    int j = tid & 63, i0 = tid >> 6;
    for (int ii = 0; ii < 16; ++ii) {
        int i = i0 * 16 + ii;
        float a = 0.f;
#pragma unroll 8
        for (int k = 0; k < 64; ++k) a = fmaf(w2[i * 64 + k], c1s[k * 64 + j], a);
        w2c1[i * 64 + j] = a;
    }
    if (tid < 64) {
        float a = 0.f;
#pragma unroll 8
        for (int k = 0; k < 64; ++k) a = fmaf(b2[k], c1s[k * 64 + tid], a);
        b2c1[tid] = a;
    }
}

// ---- CSR count, XCD-octant partitioned ----
__global__ __launch_bounds__(256) void count_dst_oct(
    const int* __restrict__ ei, unsigned* __restrict__ counts)
{
    int oct = blockIdx.x & 7;
    int grp = blockIdx.x >> 3;
    int lo = oct * OCT_N, hi = lo + OCT_N;
    int beg = grp * FB_CE;
    int end = min(beg + FB_CE, E_TOT);
    for (int base = beg; base < end; base += 256) {
        int e = base + threadIdx.x;
        if (e < end) {
            int dst = (e < N_EDGES) ? ei[N_EDGES + e] : (e - N_EDGES);
            if (dst >= lo && dst < hi) atomicAdd(&counts[dst], 1u);
        }
    }
}

// ---- two-level scan: block-local exclusive scan + block totals ----
__global__ __launch_bounds__(1024) void scan_block(
    const unsigned* __restrict__ counts,
    unsigned* __restrict__ excl, unsigned* __restrict__ partial)
{
    __shared__ unsigned wt[16], wo[16];
    int tid = threadIdx.x, lane = tid & 63, wid = tid >> 6;
    int i = blockIdx.x * 1024 + tid;
    unsigned v = (i < N_NODES) ? counts[i] : 0u;
    unsigned xs = v;
#pragma unroll
    for (int off = 1; off < 64; off <<= 1) {
        unsigned t = __shfl_up(xs, off, 64);
        if (lane >= off) xs += t;
    }
    if (lane == 63) wt[wid] = xs;
    __syncthreads();
    if (tid == 0) {
        unsigned run = 0;
        for (int w = 0; w < 16; ++w) { wo[w] = run; run += wt[w]; }
        partial[blockIdx.x] = run;
    }
    __syncthreads();
    if (i < N_NODES) excl[i] = wo[wid] + xs - v;
}

// ---- finalize scan -> row_ptr & cursor; init pool + As slots ----
__global__ __launch_bounds__(256) void scan_add(
    const unsigned* __restrict__ excl, const unsigned* __restrict__ partial,
    unsigned* __restrict__ row_ptr, unsigned* __restrict__ cursor,
    unsigned* __restrict__ g_enc, unsigned* __restrict__ As1, unsigned* __restrict__ As2)
{
    int tid = threadIdx.x, lane = tid & 63;
    int bg = blockIdx.x >> 2;                 // 1024-group index (uniform per block)
    unsigned pv = (lane < bg) ? partial[lane] : 0u;   // bg <= 48 < 64
#pragma unroll
    for (int off = 32; off; off >>= 1) pv += __shfl_xor(pv, off, 64);
    int i = blockIdx.x * 256 + tid;
    if (i < N_NODES) {
        unsigned r = excl[i] + pv;
        row_ptr[i] = r;
        cursor[i]  = r;
    }
    if (i == 0) row_ptr[N_NODES] = E_TOT;
    if (blockIdx.x == 0) {
        for (int j = tid; j < N_GRAPHS * HIDDEN; j += 256)
            g_enc[j] = fenc(-INFINITY);
        if (tid == 0) { As1[0] = fenc(-INFINITY); As2[0] = fenc(-INFINITY); }
    }
}

// ---- CSR fill, XCD-octant partitioned ----
__global__ __launch_bounds__(256) void fill_csr_oct(
    const int* __restrict__ ei,
    unsigned* __restrict__ cursor, int* __restrict__ csr_src)
{
    int oct = blockIdx.x & 7;
    int grp = blockIdx.x >> 3;
    int lo = oct * OCT_N, hi = lo + OCT_N;
    int beg = grp * FB_CE;
    int end = min(beg + FB_CE, E_TOT);
    for (int base = beg; base < end; base += 256) {
        int e = base + threadIdx.x;
        if (e < end) {
            int dst = (e < N_EDGES) ? ei[N_EDGES + e] : (e - N_EDGES);
            if (dst >= lo && dst < hi) {
                int src = (e < N_EDGES) ? ei[e] : dst;
                unsigned pos = atomicAdd(&cursor[dst], 1u);
                csr_src[pos] = src;
            }
        }
    }
}

// ---- fused: node MLP + folded (w2@c1w) linear + alpha dots, 8 nodes/wave ----
__global__ __launch_bounds__(256) void embed_gemm1(
    const float* __restrict__ x,
    const float* __restrict__ n_w1, const float* __restrict__ n_b1,
    const float* __restrict__ w2c1, const float* __restrict__ b2c1,
    const float* __restrict__ a1s, const float* __restrict__ a1d,
    __half* __restrict__ hlin, float* __restrict__ asrc, float* __restrict__ adst,
    unsigned* __restrict__ As1)
{
    __shared__ float wred[4];
    int lane = threadIdx.x & 63, w = threadIdx.x >> 6;
    int n0 = blockIdx.x * 32 + w * 8;
    if (n0 < N_NODES) {
        float acc[8];
        float b1v = n_b1[lane];
#pragma unroll
        for (int nn = 0; nn < 8; ++nn) acc[nn] = b1v;
        const float* xb = x + (size_t)n0 * N_FEAT;
#pragma unroll 4
        for (int k = 0; k < N_FEAT; ++k) {
            float wv = n_w1[k * 64 + lane];
#pragma unroll
            for (int nn = 0; nn < 8; ++nn)
                acc[nn] = fmaf(xb[(size_t)nn * N_FEAT + k], wv, acc[nn]);
        }
#pragma unroll
        for (int nn = 0; nn < 8; ++nn) acc[nn] = fmaxf(acc[nn], 0.f);
        float hl[8];
        float bcv = b2c1[lane];
#pragma unroll
        for (int nn = 0; nn < 8; ++nn) hl[nn] = bcv;
        for (int k = 0; k < 64; ++k) {
            float wv = w2c1[k * 64 + lane];
#pragma unroll
            for (int nn = 0; nn < 8; ++nn)
                hl[nn] = fmaf(__shfl(acc[nn], k, 64), wv, hl[nn]);
        }
        float s1v = a1s[lane], d1v = a1d[lane];
        float wmax = -INFINITY;
#pragma unroll
        for (int nn = 0; nn < 8; ++nn) {
            int n = n0 + nn;
            hlin[(size_t)n * 64 + lane] = __float2half(hl[nn]);
            float ps = hl[nn] * s1v, pd = hl[nn] * d1v;
#pragma unroll
            for (int off = 32; off; off >>= 1) {
                ps += __shfl_xor(ps, off, 64);
                pd += __shfl_xor(pd, off, 64);
            }
            if (lane == 0) { asrc[n] = ps; adst[n] = pd; wmax = fmaxf(wmax, ps); }
        }
        if (lane == 0) wred[w] = wmax;
    } else if ((threadIdx.x & 63) == 0) wred[w] = -INFINITY;
    __syncthreads();
    if (threadIdx.x == 0) {
        float m = fmaxf(fmaxf(wred[0], wred[1]), fmaxf(wred[2], wred[3]));
        atomicMax(As1, fenc(m));
    }
}

// ---- single-pass weighted aggregation with global-offset softmax ----
__device__ __forceinline__ float agg_pass(
    const __half* __restrict__ hmat, const float* __restrict__ asrc,
    const int* __restrict__ csr_src, int s0, int s1, float ad, float C, int lane)
{
    float acc0 = 0.f, acc1 = 0.f, acc2 = 0.f, acc3 = 0.f, sden = 0.f;
    for (int base = s0; base < s1; base += 64) {
        int i = base + lane;
        int idx = 0; float wgt = 0.f;
        if (i < s1) {
            idx = csr_src[i];
            wgt = __expf(lrelu(asrc[idx] + ad) - C);
        }
        sden += wgt;
        int cnt = min(64, s1 - base);
        int j = 0;
        for (; j + 3 < cnt; j += 4) {
            int sa = __shfl(idx, j, 64);     float wa = __shfl(wgt, j, 64);
            int sb = __shfl(idx, j + 1, 64); float wb = __shfl(wgt, j + 1, 64);
            int sc = __shfl(idx, j + 2, 64); float wc = __shfl(wgt, j + 2, 64);
            int sd = __shfl(idx, j + 3, 64); float wd = __shfl(wgt, j + 3, 64);
            acc0 = fmaf(wa, __half2float(hmat[(size_t)sa * 64 + lane]), acc0);
            acc1 = fmaf(wb, __half2float(hmat[(size_t)sb * 64 + lane]), acc1);
            acc2 = fmaf(wc, __half2float(hmat[(size_t)sc * 64 + lane]), acc2);
            acc3 = fmaf(wd, __half2float(hmat[(size_t)sd * 64 + lane]), acc3);
        }
        for (; j < cnt; ++j) {
            int sn = __shfl(idx, j, 64); float wj = __shfl(wgt, j, 64);
            acc0 = fmaf(wj, __half2float(hmat[(size_t)sn * 64 + lane]), acc0);
        }
    }
#pragma unroll
    for (int off = 32; off; off >>= 1) sden += __shfl_xor(sden, off, 64);
    return (acc0 + acc1 + acc2 + acc3) / (sden + 1e-30f);
}

// ---- fused: GAT layer1 aggregate (+relu) + layer2 linear + alpha dots ----
__global__ __launch_bounds__(256) void agg1_gemm2(
    const __half* __restrict__ hlin1,
    const float* __restrict__ asrc, const float* __restrict__ adst,
    const unsigned* __restrict__ row_ptr, const int* __restrict__ csr_src,
    const unsigned* __restrict__ As1,
    const float* __restrict__ c1b,
    const float* __restrict__ c2w, const float* __restrict__ a2s, const float* __restrict__ a2d,
    __half* __restrict__ hlin2, float* __restrict__ asrc2, float* __restrict__ adst2,
    unsigned* __restrict__ As2)
{
    __shared__ float wred[4];
    int lane = threadIdx.x & 63, w = threadIdx.x >> 6;
    int d = blockIdx.x * 4 + w;
    int s0 = (int)row_ptr[d], s1 = (int)row_ptr[d + 1];
    float ad = adst[d];
    float C = lrelu(fdec(As1[0]) + ad);       // >= every edge's e for this dst
    float agg = agg_pass(hlin1, asrc, csr_src, s0, s1, ad, C, lane);
    float v = fmaxf(agg + c1b[lane], 0.f);    // + bias, relu
    float hl = 0.f;
#pragma unroll 8
    for (int k = 0; k < 64; ++k)
        hl = fmaf(__shfl(v, k, 64), c2w[k * 64 + lane], hl);
    hlin2[(size_t)d * 64 + lane] = __float2half(hl);
    float ps = hl * a2s[lane], pd = hl * a2d[lane];
#pragma unroll
    for (int off = 32; off; off >>= 1) {
        ps += __shfl_xor(ps, off, 64);
        pd += __shfl_xor(pd, off, 64);
    }
    if (lane == 0) { asrc2[d] = ps; adst2[d] = pd; wred[w] = ps; }
    __syncthreads();
    if (threadIdx.x == 0) {
        float m = fmaxf(fmaxf(wred[0], wred[1]), fmaxf(wred[2], wred[3]));
        atomicMax(As2, fenc(m));
    }
}

// ---- fused: GAT layer2 aggregate + bias + global max pool ----
__global__ __launch_bounds__(256) void agg2_pool(
    const __half* __restrict__ hlin2,
    const float* __restrict__ asrc, const float* __restrict__ adst,
    const unsigned* __restrict__ row_ptr, const int* __restrict__ csr_src,
    const unsigned* __restrict__ As2,
    const float* __restrict__ c2b, const int* __restrict__ batch,
    unsigned* __restrict__ g_enc)
{
    int lane = threadIdx.x & 63;
    int d = blockIdx.x * 4 + (threadIdx.x >> 6);
    int s0 = (int)row_ptr[d], s1 = (int)row_ptr[d + 1];
    float ad = adst[d];
    float C = lrelu(fdec(As2[0]) + ad);
    float agg = agg_pass(hlin2, asrc, csr_src, s0, s1, ad, C, lane);
    float v = agg + c2b[lane];                // no relu
    atomicMax(&g_enc[batch[d] * 64 + lane], fenc(v));
}

// ---- readout MLP: wave per graph ----
__global__ __launch_bounds__(256) void readout(
    const unsigned* __restrict__ g_enc,
    const float* __restrict__ fc1w, const float* __restrict__ fc1b,
    const float* __restrict__ fc2w, const float* __restrict__ fc2b,
    float* __restrict__ out)
{
    int lane = threadIdx.x & 63;
    int gi = blockIdx.x * 4 + (threadIdx.x >> 6);
    float gv = fdec(g_enc[gi * 64 + lane]);
    float a = fc1b[lane];
#pragma unroll 8
    for (int k = 0; k < 64; ++k)
        a = fmaf(__shfl(gv, k, 64), fc1w[k * 64 + lane], a);
    a = fmaxf(a, 0.f) * fc2w[lane];
#pragma unroll
    for (int off = 32; off; off >>= 1) a += __shfl_xor(a, off, 64);
    if (lane == 0) out[gi] = a + fc2b[0];
}

extern "C" void kernel_launch(void* const* d_in, const int* in_sizes, int n_in,
                              void* d_out, int out_size, void* d_ws, size_t ws_size,
                              hipStream_t stream)
{
    const float* x      = (const float*)d_in[0];
    const int*   ei     = (const int*)d_in[1];
    // d_in[2] edge_attr: dead value in reference, never read
    const int*   batch  = (const int*)d_in[3];
    const float* n_w1   = (const float*)d_in[4];
    const float* n_b1   = (const float*)d_in[5];
    const float* n_w2   = (const float*)d_in[6];
    const float* n_b2   = (const float*)d_in[7];
    // d_in[8..11] edge MLP weights: dead
    const float* c1_w    = (const float*)d_in[12];
    const float* c1_asrc = (const float*)d_in[13];
    const float* c1_adst = (const float*)d_in[14];
    const float* c1_b    = (const float*)d_in[15];
    const float* c2_w    = (const float*)d_in[16];
    const float* c2_asrc = (const float*)d_in[17];
    const float* c2_adst = (const float*)d_in[18];
    const float* c2_b    = (const float*)d_in[19];
    const float* fc1_w   = (const float*)d_in[20];
    const float* fc1_b   = (const float*)d_in[21];
    const float* fc2_w   = (const float*)d_in[22];
    const float* fc2_b   = (const float*)d_in[23];
    float* out = (float*)d_out;

    // workspace carve (256B aligned)
    char* ws = (char*)d_ws;
    size_t off = 0;
    auto alloc = [&](size_t bytes) -> void* {
        off = (off + 255) & ~(size_t)255;
        void* p = ws + off;
        off += bytes;
        return p;
    };
    unsigned* counts  = (unsigned*)alloc(sizeof(unsigned) * N_NODES);
    unsigned* excl    = (unsigned*)alloc(sizeof(unsigned) * N_NODES);
    unsigned* partial = (unsigned*)alloc(sizeof(unsigned) * (NB_SCAN + 1));
    unsigned* row_ptr = (unsigned*)alloc(sizeof(unsigned) * (N_NODES + 1));
    unsigned* cursor  = (unsigned*)alloc(sizeof(unsigned) * N_NODES);
    int*      csr_src = (int*)alloc(sizeof(int) * E_TOT);
    __half*   hlin1   = (__half*)alloc(sizeof(__half) * (size_t)N_NODES * 64);
    __half*   hlin2   = (__half*)alloc(sizeof(__half) * (size_t)N_NODES * 64);
    float*    asrc1   = (float*)alloc(sizeof(float) * N_NODES);
    float*    adst1   = (float*)alloc(sizeof(float) * N_NODES);
    float*    asrc2   = (float*)alloc(sizeof(float) * N_NODES);
    float*    adst2   = (float*)alloc(sizeof(float) * N_NODES);
    unsigned* g_enc   = (unsigned*)alloc(sizeof(unsigned) * N_GRAPHS * HIDDEN);
    float*    w2c1    = (float*)alloc(sizeof(float) * 64 * 64);
    float*    b2c1    = (float*)alloc(sizeof(float) * 64);
    unsigned* As1     = (unsigned*)alloc(sizeof(unsigned) * 2);
    unsigned* As2     = (unsigned*)alloc(sizeof(unsigned) * 2);

    // CSR build + weight fold
    hipMemsetAsync(counts, 0, sizeof(unsigned) * N_NODES, stream);
    fold_w<<<1, 256, 0, stream>>>(n_w2, n_b2, c1_w, w2c1, b2c1);
    count_dst_oct<<<8 * FB_GRP, 256, 0, stream>>>(ei, counts);
    scan_block<<<NB_SCAN, 1024, 0, stream>>>(counts, excl, partial);
    scan_add<<<(N_NODES + 255) / 256, 256, 0, stream>>>(excl, partial, row_ptr, cursor,
                                                        g_enc, As1, As2);
    fill_csr_oct<<<8 * FB_GRP, 256, 0, stream>>>(ei, cursor, csr_src);

    // fused pipeline
    embed_gemm1<<<(N_NODES + 31) / 32, 256, 0, stream>>>(
        x, n_w1, n_b1, w2c1, b2c1, c1_asrc, c1_adst, hlin1, asrc1, adst1, As1);
    agg1_gemm2<<<N_NODES / 4, 256, 0, stream>>>(
        hlin1, asrc1, adst1, row_ptr, csr_src, As1,
        c1_b, c2_w, c2_asrc, c2_adst, hlin2, asrc2, adst2, As2);
    agg2_pool<<<N_NODES / 4, 256, 0, stream>>>(
        hlin2, asrc2, adst2, row_ptr, csr_src, As2, c2_b, batch, g_enc);
    readout<<<N_GRAPHS / 4, 256, 0, stream>>>(g_enc, fc1_w, fc1_b, fc2_w, fc2_b, out);
}

// Round 5
// 456.910 us; speedup vs baseline: 1.0621x; 1.0621x over previous
//
#include <hip/hip_runtime.h>
#include <hip/hip_fp16.h>
#include <math.h>

#define N_NODES   50000
#define N_EDGES   1600000
#define E_TOT     (N_EDGES + N_NODES)
#define N_FEAT    128
#define HIDDEN    64
#define N_GRAPHS  128
#define NEG_SLOPE 0.2f
#define NB_SCAN   ((N_NODES + 1023) / 1024)
#define OCT_N     (N_NODES / 8)          // 6250, exact
#define FB_GRP    96                     // edge-slices per octant
#define FB_CE     ((E_TOT + FB_GRP - 1) / FB_GRP)
#define EMB_B     ((N_NODES + 31) / 32)  // embed blocks (8 nodes/wave, 4 waves)
#define AGG_B     (N_NODES / 4)          // agg blocks (1 dst/wave)

// ---- monotone float<->uint encoding for atomicMax on floats ----
__device__ __forceinline__ unsigned fenc(float f) {
    unsigned u = __float_as_uint(f);
    return (u & 0x80000000u) ? ~u : (u | 0x80000000u);
}
__device__ __forceinline__ float fdec(unsigned k) {
    unsigned u = (k & 0x80000000u) ? (k & 0x7FFFFFFFu) : ~k;
    return __uint_as_float(u);
}
__device__ __forceinline__ float lrelu(float e) {
    return (e >= 0.f) ? e : NEG_SLOPE * e;
}

// ---- fold: W2C1 = w2 @ c1w ; B2C1 = b2 @ c1w (one block) ----
__global__ __launch_bounds__(256) void fold_w(
    const float* __restrict__ w2, const float* __restrict__ b2,
    const float* __restrict__ c1w,
    float* __restrict__ w2c1, float* __restrict__ b2c1)
{
    __shared__ float c1s[64 * 64];
    int tid = threadIdx.x;
    for (int i = tid; i < 4096; i += 256) c1s[i] = c1w[i];
    __syncthreads();
    int j = tid & 63, i0 = tid >> 6;
    for (int ii = 0; ii < 16; ++ii) {
        int i = i0 * 16 + ii;
        float a = 0.f;
#pragma unroll 8
        for (int k = 0; k < 64; ++k) a = fmaf(w2[i * 64 + k], c1s[k * 64 + j], a);
        w2c1[i * 64 + j] = a;
    }
    if (tid < 64) {
        float a = 0.f;
#pragma unroll 8
        for (int k = 0; k < 64; ++k) a = fmaf(b2[k], c1s[k * 64 + tid], a);
        b2c1[tid] = a;
    }
}

// ---- CSR count (plain single pass; atomics spread over 50K addresses) ----
__global__ void count_dst(const int* __restrict__ ei, unsigned* __restrict__ counts) {
    int e = blockIdx.x * 256 + threadIdx.x;
    if (e >= E_TOT) return;
    int dst = (e < N_EDGES) ? ei[N_EDGES + e] : (e - N_EDGES);
    atomicAdd(&counts[dst], 1u);
}

// ---- two-level scan: block-local exclusive scan + block totals ----
__global__ __launch_bounds__(1024) void scan_block(
    const unsigned* __restrict__ counts,
    unsigned* __restrict__ excl, unsigned* __restrict__ partial)
{
    __shared__ unsigned wt[16], wo[16];
    int tid = threadIdx.x, lane = tid & 63, wid = tid >> 6;
    int i = blockIdx.x * 1024 + tid;
    unsigned v = (i < N_NODES) ? counts[i] : 0u;
    unsigned xs = v;
#pragma unroll
    for (int off = 1; off < 64; off <<= 1) {
        unsigned t = __shfl_up(xs, off, 64);
        if (lane >= off) xs += t;
    }
    if (lane == 63) wt[wid] = xs;
    __syncthreads();
    if (tid == 0) {
        unsigned run = 0;
        for (int w = 0; w < 16; ++w) { wo[w] = run; run += wt[w]; }
        partial[blockIdx.x] = run;
    }
    __syncthreads();
    if (i < N_NODES) excl[i] = wo[wid] + xs - v;
}

// ---- finalize scan -> row_ptr & cursor; init pool ----
__global__ __launch_bounds__(256) void scan_add(
    const unsigned* __restrict__ excl, const unsigned* __restrict__ partial,
    unsigned* __restrict__ row_ptr, unsigned* __restrict__ cursor,
    unsigned* __restrict__ g_enc)
{
    int tid = threadIdx.x, lane = tid & 63;
    int bg = blockIdx.x >> 2;                 // 1024-group index (uniform per block)
    unsigned pv = (lane < bg) ? partial[lane] : 0u;   // bg <= 48 < 64
#pragma unroll
    for (int off = 32; off; off >>= 1) pv += __shfl_xor(pv, off, 64);
    int i = blockIdx.x * 256 + tid;
    if (i < N_NODES) {
        unsigned r = excl[i] + pv;
        row_ptr[i] = r;
        cursor[i]  = r;
    }
    if (i == 0) row_ptr[N_NODES] = E_TOT;
    if (blockIdx.x == 0) {
        for (int j = tid; j < N_GRAPHS * HIDDEN; j += 256)
            g_enc[j] = fenc(-INFINITY);
    }
}

// ---- CSR fill, XCD-octant partitioned (scattered stores stay XCD-local) ----
__global__ __launch_bounds__(256) void fill_csr_oct(
    const int* __restrict__ ei,
    unsigned* __restrict__ cursor, int* __restrict__ csr_src)
{
    int oct = blockIdx.x & 7;
    int grp = blockIdx.x >> 3;
    int lo = oct * OCT_N, hi = lo + OCT_N;
    int beg = grp * FB_CE;
    int end = min(beg + FB_CE, E_TOT);
    for (int base = beg; base < end; base += 256) {
        int e = base + threadIdx.x;
        if (e < end) {
            int dst = (e < N_EDGES) ? ei[N_EDGES + e] : (e - N_EDGES);
            if (dst >= lo && dst < hi) {
                int src = (e < N_EDGES) ? ei[e] : dst;
                unsigned pos = atomicAdd(&cursor[dst], 1u);
                csr_src[pos] = src;
            }
        }
    }
}

// ---- 1-block max-reduce of per-block maxima -> As[0] ----
__global__ __launch_bounds__(1024) void reduce_max(
    const float* __restrict__ in, int n, float* __restrict__ As)
{
    __shared__ float wm[16];
    int tid = threadIdx.x, lane = tid & 63, wid = tid >> 6;
    float m = -INFINITY;
    for (int i = tid; i < n; i += 1024) m = fmaxf(m, in[i]);
#pragma unroll
    for (int off = 32; off; off >>= 1) m = fmaxf(m, __shfl_xor(m, off, 64));
    if (lane == 0) wm[wid] = m;
    __syncthreads();
    if (tid == 0) {
        float r = -INFINITY;
        for (int w = 0; w < 16; ++w) r = fmaxf(r, wm[w]);
        As[0] = r;
    }
}

// ---- fused: node MLP + folded (w2@c1w) linear + alpha dots, 8 nodes/wave ----
// writes split-half feature arrays hlo/hhi (each [N][32] half)
__global__ __launch_bounds__(256) void embed_gemm1(
    const float* __restrict__ x,
    const float* __restrict__ n_w1, const float* __restrict__ n_b1,
    const float* __restrict__ w2c1, const float* __restrict__ b2c1,
    const float* __restrict__ a1s, const float* __restrict__ a1d,
    __half* __restrict__ hlo, __half* __restrict__ hhi,
    float* __restrict__ asrc, float* __restrict__ adst,
    float* __restrict__ blkmax)
{
    __shared__ float wred[4];
    int lane = threadIdx.x & 63, w = threadIdx.x >> 6;
    int n0 = blockIdx.x * 32 + w * 8;
    if (n0 < N_NODES) {
        float acc[8];
        float b1v = n_b1[lane];
#pragma unroll
        for (int nn = 0; nn < 8; ++nn) acc[nn] = b1v;
        const float* xb = x + (size_t)n0 * N_FEAT;
#pragma unroll 4
        for (int k = 0; k < N_FEAT; ++k) {
            float wv = n_w1[k * 64 + lane];
#pragma unroll
            for (int nn = 0; nn < 8; ++nn)
                acc[nn] = fmaf(xb[(size_t)nn * N_FEAT + k], wv, acc[nn]);
        }
#pragma unroll
        for (int nn = 0; nn < 8; ++nn) acc[nn] = fmaxf(acc[nn], 0.f);
        float hl[8];
        float bcv = b2c1[lane];
#pragma unroll
        for (int nn = 0; nn < 8; ++nn) hl[nn] = bcv;
        for (int k = 0; k < 64; ++k) {
            float wv = w2c1[k * 64 + lane];
#pragma unroll
            for (int nn = 0; nn < 8; ++nn)
                hl[nn] = fmaf(__shfl(acc[nn], k, 64), wv, hl[nn]);
        }
        float s1v = a1s[lane], d1v = a1d[lane];
        float wmax = -INFINITY;
#pragma unroll
        for (int nn = 0; nn < 8; ++nn) {
            int n = n0 + nn;
            if (lane < 32) hlo[(size_t)n * 32 + lane]        = __float2half(hl[nn]);
            else           hhi[(size_t)n * 32 + (lane - 32)] = __float2half(hl[nn]);
            float ps = hl[nn] * s1v, pd = hl[nn] * d1v;
#pragma unroll
            for (int off = 32; off; off >>= 1) {
                ps += __shfl_xor(ps, off, 64);
                pd += __shfl_xor(pd, off, 64);
            }
            if (lane == 0) { asrc[n] = ps; adst[n] = pd; wmax = fmaxf(wmax, ps); }
        }
        if (lane == 0) wred[w] = wmax;
    } else if ((threadIdx.x & 63) == 0) wred[w] = -INFINITY;
    __syncthreads();
    if (threadIdx.x == 0)
        blkmax[blockIdx.x] = fmaxf(fmaxf(wred[0], wred[1]), fmaxf(wred[2], wred[3]));
}

// ---- half-feature weighted aggregation; 2 edges/iter (lane = 32*p + f) ----
// returns UNNORMALIZED sum for feature f31 (all lanes), den in den_out
__device__ __forceinline__ float agg_half(
    const __half* __restrict__ hmat,      // [N][32] half array for this half
    const float* __restrict__ asrc,
    const int* __restrict__ csr_src, int s0, int s1, float ad, float C,
    int lane, float& den_out)
{
    int f31 = lane & 31;
    int p = lane >> 5;
    float acc0 = 0.f, acc1 = 0.f, acc2 = 0.f, acc3 = 0.f, sden = 0.f;
    for (int base = s0; base < s1; base += 64) {
        int i = base + lane;
        int idx = 0; float wgt = 0.f;
        if (i < s1) {
            idx = csr_src[i];
            wgt = __expf(lrelu(asrc[idx] + ad) - C);
        }
        sden += wgt;
        int cnt = min(64, s1 - base);
        int j = 0;
        for (; j + 7 < cnt; j += 8) {       // 8 edges, 4 loads in flight
            int sa = __shfl(idx, j     + p, 64); float wa = __shfl(wgt, j     + p, 64);
            int sb = __shfl(idx, j + 2 + p, 64); float wb = __shfl(wgt, j + 2 + p, 64);
            int sc = __shfl(idx, j + 4 + p, 64); float wc = __shfl(wgt, j + 4 + p, 64);
            int sd = __shfl(idx, j + 6 + p, 64); float wd = __shfl(wgt, j + 6 + p, 64);
            acc0 = fmaf(wa, __half2float(hmat[(size_t)sa * 32 + f31]), acc0);
            acc1 = fmaf(wb, __half2float(hmat[(size_t)sb * 32 + f31]), acc1);
            acc2 = fmaf(wc, __half2float(hmat[(size_t)sc * 32 + f31]), acc2);
            acc3 = fmaf(wd, __half2float(hmat[(size_t)sd * 32 + f31]), acc3);
        }
        for (; j < cnt; j += 2) {           // tail; beyond-range staged slots wgt=0
            int sa = __shfl(idx, j + p, 64); float wa = __shfl(wgt, j + p, 64);
            acc0 = fmaf(wa, __half2float(hmat[(size_t)sa * 32 + f31]), acc0);
        }
    }
    float acc = acc0 + acc1 + acc2 + acc3;
    acc += __shfl_xor(acc, 32, 64);         // combine edge parities
#pragma unroll
    for (int off = 32; off; off >>= 1) sden += __shfl_xor(sden, off, 64);
    den_out = sden;
    return acc;
}

// ---- layer1 agg, low half: v_lo = relu(agg/den + c1b[f]) ----
__global__ __launch_bounds__(256) void agg1_lo(
    const __half* __restrict__ hlo1,
    const float* __restrict__ asrc, const float* __restrict__ adst,
    const unsigned* __restrict__ row_ptr, const int* __restrict__ csr_src,
    const float* __restrict__ As1, const float* __restrict__ c1b,
    float* __restrict__ v_lo)
{
    int lane = threadIdx.x & 63;
    int d = blockIdx.x * 4 + (threadIdx.x >> 6);
    int s0 = (int)row_ptr[d], s1 = (int)row_ptr[d + 1];
    float ad = adst[d];
    float C = lrelu(As1[0] + ad);
    float den;
    float acc = agg_half(hlo1, asrc, csr_src, s0, s1, ad, C, lane, den);
    if (lane < 32)
        v_lo[(size_t)d * 32 + lane] = fmaxf(acc / (den + 1e-30f) + c1b[lane], 0.f);
}

// ---- layer1 agg, high half + layer2 linear + alpha dots ----
__global__ __launch_bounds__(256) void agg1_hi(
    const __half* __restrict__ hhi1,
    const float* __restrict__ asrc, const float* __restrict__ adst,
    const unsigned* __restrict__ row_ptr, const int* __restrict__ csr_src,
    const float* __restrict__ As1, const float* __restrict__ c1b,
    const float* __restrict__ v_lo,
    const float* __restrict__ c2w, const float* __restrict__ a2s, const float* __restrict__ a2d,
    __half* __restrict__ hlo2, __half* __restrict__ hhi2,
    float* __restrict__ asrc2, float* __restrict__ adst2,
    float* __restrict__ blkmax)
{
    __shared__ float wred[4];
    int lane = threadIdx.x & 63, w = threadIdx.x >> 6;
    int d = blockIdx.x * 4 + w;
    int s0 = (int)row_ptr[d], s1 = (int)row_ptr[d + 1];
    float ad = adst[d];
    float C = lrelu(As1[0] + ad);
    float den;
    float acc = agg_half(hhi1, asrc, csr_src, s0, s1, ad, C, lane, den);
    float v_hi = fmaxf(acc / (den + 1e-30f) + c1b[32 + (lane & 31)], 0.f);
    // assemble full 64-dim v: lanes 0-31 load v_lo, lanes 32-63 keep v_hi
    float v = (lane < 32) ? v_lo[(size_t)d * 32 + lane] : v_hi;
    // layer-2 linear
    float hl = 0.f;
#pragma unroll 8
    for (int k = 0; k < 64; ++k)
        hl = fmaf(__shfl(v, k, 64), c2w[k * 64 + lane], hl);
    if (lane < 32) hlo2[(size_t)d * 32 + lane]        = __float2half(hl);
    else           hhi2[(size_t)d * 32 + (lane - 32)] = __float2half(hl);
    float ps = hl * a2s[lane], pd = hl * a2d[lane];
#pragma unroll
    for (int off = 32; off; off >>= 1) {
        ps += __shfl_xor(ps, off, 64);
        pd += __shfl_xor(pd, off, 64);
    }
    if (lane == 0) { asrc2[d] = ps; adst2[d] = pd; wred[w] = ps; }
    __syncthreads();
    if (threadIdx.x == 0)
        blkmax[blockIdx.x] = fmaxf(fmaxf(wred[0], wred[1]), fmaxf(wred[2], wred[3]));
}

// ---- layer2 agg half + bias + global max pool (half features) ----
template <int HALF>
__global__ __launch_bounds__(256) void agg2_pool(
    const __half* __restrict__ h2,
    const float* __restrict__ asrc, const float* __restrict__ adst,
    const unsigned* __restrict__ row_ptr, const int* __restrict__ csr_src,
    const float* __restrict__ As2, const float* __restrict__ c2b,
    const int* __restrict__ batch, unsigned* __restrict__ g_enc)
{
    int lane = threadIdx.x & 63;
    int d = blockIdx.x * 4 + (threadIdx.x >> 6);
    int s0 = (int)row_ptr[d], s1 = (int)row_ptr[d + 1];
    float ad = adst[d];
    float C = lrelu(As2[0] + ad);
    float den;
    float acc = agg_half(h2, asrc, csr_src, s0, s1, ad, C, lane, den);
    if (lane < 32) {
        float v = acc / (den + 1e-30f) + c2b[HALF * 32 + lane];
        atomicMax(&g_enc[batch[d] * 64 + HALF * 32 + lane], fenc(v));
    }
}

// ---- readout MLP: wave per graph ----
__global__ __launch_bounds__(256) void readout(
    const unsigned* __restrict__ g_enc,
    const float* __restrict__ fc1w, const float* __restrict__ fc1b,
    const float* __restrict__ fc2w, const float* __restrict__ fc2b,
    float* __restrict__ out)
{
    int lane = threadIdx.x & 63;
    int gi = blockIdx.x * 4 + (threadIdx.x >> 6);
    float gv = fdec(g_enc[gi * 64 + lane]);
    float a = fc1b[lane];
#pragma unroll 8
    for (int k = 0; k < 64; ++k)
        a = fmaf(__shfl(gv, k, 64), fc1w[k * 64 + lane], a);
    a = fmaxf(a, 0.f) * fc2w[lane];
#pragma unroll
    for (int off = 32; off; off >>= 1) a += __shfl_xor(a, off, 64);
    if (lane == 0) out[gi] = a + fc2b[0];
}

extern "C" void kernel_launch(void* const* d_in, const int* in_sizes, int n_in,
                              void* d_out, int out_size, void* d_ws, size_t ws_size,
                              hipStream_t stream)
{
    const float* x      = (const float*)d_in[0];
    const int*   ei     = (const int*)d_in[1];
    // d_in[2] edge_attr: dead value in reference, never read
    const int*   batch  = (const int*)d_in[3];
    const float* n_w1   = (const float*)d_in[4];
    const float* n_b1   = (const float*)d_in[5];
    const float* n_w2   = (const float*)d_in[6];
    const float* n_b2   = (const float*)d_in[7];
    // d_in[8..11] edge MLP weights: dead
    const float* c1_w    = (const float*)d_in[12];
    const float* c1_asrc = (const float*)d_in[13];
    const float* c1_adst = (const float*)d_in[14];
    const float* c1_b    = (const float*)d_in[15];
    const float* c2_w    = (const float*)d_in[16];
    const float* c2_asrc = (const float*)d_in[17];
    const float* c2_adst = (const float*)d_in[18];
    const float* c2_b    = (const float*)d_in[19];
    const float* fc1_w   = (const float*)d_in[20];
    const float* fc1_b   = (const float*)d_in[21];
    const float* fc2_w   = (const float*)d_in[22];
    const float* fc2_b   = (const float*)d_in[23];
    float* out = (float*)d_out;

    // workspace carve (256B aligned)
    char* ws = (char*)d_ws;
    size_t off = 0;
    auto alloc = [&](size_t bytes) -> void* {
        off = (off + 255) & ~(size_t)255;
        void* p = ws + off;
        off += bytes;
        return p;
    };
    unsigned* counts  = (unsigned*)alloc(sizeof(unsigned) * N_NODES);
    unsigned* excl    = (unsigned*)alloc(sizeof(unsigned) * N_NODES);
    unsigned* partial = (unsigned*)alloc(sizeof(unsigned) * (NB_SCAN + 1));
    unsigned* row_ptr = (unsigned*)alloc(sizeof(unsigned) * (N_NODES + 1));
    unsigned* cursor  = (unsigned*)alloc(sizeof(unsigned) * N_NODES);
    int*      csr_src = (int*)alloc(sizeof(int) * E_TOT);
    __half*   hlo1    = (__half*)alloc(sizeof(__half) * (size_t)N_NODES * 32);
    __half*   hhi1    = (__half*)alloc(sizeof(__half) * (size_t)N_NODES * 32);
    __half*   hlo2    = (__half*)alloc(sizeof(__half) * (size_t)N_NODES * 32);
    __half*   hhi2    = (__half*)alloc(sizeof(__half) * (size_t)N_NODES * 32);
    float*    v_lo    = (float*)alloc(sizeof(float) * (size_t)N_NODES * 32);
    float*    asrc1   = (float*)alloc(sizeof(float) * N_NODES);
    float*    adst1   = (float*)alloc(sizeof(float) * N_NODES);
    float*    asrc2   = (float*)alloc(sizeof(float) * N_NODES);
    float*    adst2   = (float*)alloc(sizeof(float) * N_NODES);
    unsigned* g_enc   = (unsigned*)alloc(sizeof(unsigned) * N_GRAPHS * HIDDEN);
    float*    w2c1    = (float*)alloc(sizeof(float) * 64 * 64);
    float*    b2c1    = (float*)alloc(sizeof(float) * 64);
    float*    blkmax1 = (float*)alloc(sizeof(float) * EMB_B);
    float*    blkmax2 = (float*)alloc(sizeof(float) * AGG_B);
    float*    As1     = (float*)alloc(sizeof(float) * 2);
    float*    As2     = (float*)alloc(sizeof(float) * 2);

    // CSR build + weight fold
    hipMemsetAsync(counts, 0, sizeof(unsigned) * N_NODES, stream);
    fold_w<<<1, 256, 0, stream>>>(n_w2, n_b2, c1_w, w2c1, b2c1);
    count_dst<<<(E_TOT + 255) / 256, 256, 0, stream>>>(ei, counts);
    scan_block<<<NB_SCAN, 1024, 0, stream>>>(counts, excl, partial);
    scan_add<<<(N_NODES + 255) / 256, 256, 0, stream>>>(excl, partial, row_ptr, cursor, g_enc);
    fill_csr_oct<<<8 * FB_GRP, 256, 0, stream>>>(ei, cursor, csr_src);

    // fused pipeline
    embed_gemm1<<<EMB_B, 256, 0, stream>>>(
        x, n_w1, n_b1, w2c1, b2c1, c1_asrc, c1_adst,
        hlo1, hhi1, asrc1, adst1, blkmax1);
    reduce_max<<<1, 1024, 0, stream>>>(blkmax1, EMB_B, As1);
    agg1_lo<<<AGG_B, 256, 0, stream>>>(
        hlo1, asrc1, adst1, row_ptr, csr_src, As1, c1_b, v_lo);
    agg1_hi<<<AGG_B, 256, 0, stream>>>(
        hhi1, asrc1, adst1, row_ptr, csr_src, As1, c1_b, v_lo,
        c2_w, c2_asrc, c2_adst, hlo2, hhi2, asrc2, adst2, blkmax2);
    reduce_max<<<1, 1024, 0, stream>>>(blkmax2, AGG_B, As2);
    agg2_pool<0><<<AGG_B, 256, 0, stream>>>(
        hlo2, asrc2, adst2, row_ptr, csr_src, As2, c2_b, batch, g_enc);
    agg2_pool<1><<<AGG_B, 256, 0, stream>>>(
        hhi2, asrc2, adst2, row_ptr, csr_src, As2, c2_b, batch, g_enc);
    readout<<<N_GRAPHS / 4, 256, 0, stream>>>(g_enc, fc1_w, fc1_b, fc2_w, fc2_b, out);
}